// Round 4
// baseline (949.140 us; speedup 1.0000x reference)
//
#include <hip/hip_runtime.h>
#include <stdint.h>

// ---------------------------------------------------------------------------
// XlaQuantizedLinear: out[M,N] = (x[M,K] @ w[N,K]^T) * scaler[N]
// Round 4: 256x256 8-phase kernel with REGISTER-PIPELINED ds_reads:
// phase p issues the fragment reads consumed by phase p+1's MFMA, so the
// LDS pipe + read latency hide under MFMA (the round-2/3 structure consumed
// reads in the same phase -> serial LDS+MFMA -> 45% MfmaUtil).
//
// Per-iter schedule (tiles t=buf0, t+1=buf1; quadrants q=(mh,nh)):
//  phase | ds_read issue (for p+1)     | stage (gl_lds)        | MFMA (p)
//  P1    | B1(t)->b1        (4)        | A0,B0(t+2) (4 loads)  | q00 a0,b0
//  P2    | A1(t)->a1        (8)        | B1(t+2)               | q01 a0,b1
//  P3    | A0(t+1)->a0      (8)        | A1(t+2)               | q10 a1,b0
//  P4    | B0(t+1)->b0      (4)        | A0(t+3)               | q11 a1,b1  vmcnt(6)
//  P5    | B1(t+1)->b1      (4)        | B0(t+3)               | q00 a0,b0
//  P6    | A1(t+1)->a1      (8)        | B1(t+3)               | q01 a0,b1
//  P7    | A0(t+2)->a0 [nx] (8)        | A1(t+3)               | q10 a1,b0
//  P8    | B0(t+2)->b0 [nx] (4)        | --                    | q11 a1,b1  vmcnt(4)
// vmcnt ledger (2 loads/stage-phase, 4 at P1): after P8's vmcnt(4) the 4
// outstanding = P6,P7 stages; P4's vmcnt(6) retires through P1 (A0/B0(t+2)
// landed before their P7/P8 reads); P8's vmcnt(4) retires through P5
// (B0(t+3) landed before next-P4 read). Every LDS overwrite is >=1 full
// phase + vmem latency after the region's last ds_read issue.
// Compiler emits counted lgkmcnt for the MFMA deps (m97); sched_barrier(0)
// fences around each s_barrier pin phase boundaries.
// ---------------------------------------------------------------------------

typedef __attribute__((ext_vector_type(8))) short short8v;  // 8 bf16
typedef __attribute__((ext_vector_type(4))) short short4v;
typedef __attribute__((ext_vector_type(4))) float f32x4;

#define NXCD 8

__device__ __forceinline__ short bf16_bits(float f) {
  uint32_t u = __builtin_bit_cast(uint32_t, f);
  uint32_t r = (u + 0x7FFFu + ((u >> 16) & 1u)) >> 16;
  return (short)r;
}

__device__ __forceinline__ void gl_lds16(const void* g, void* l) {
  __builtin_amdgcn_global_load_lds(
      (const __attribute__((address_space(1))) void*)g,
      (__attribute__((address_space(3))) void*)l, 16, 0, 0);
}

// LDS map (128KB): A(buf) at buf*65536 (32KB: [256 rows][128B]),
//                  B(buf) at 32768+buf*65536.
// A lds_row = mh*128 + wr*64 + r ; B lds_row = nh*128 + wc*32 + r
// swizzle: physical kbyte = logical kbyte ^ ((lds_row&7)<<4)  (involution)

__global__ __launch_bounds__(512, 2) void gemm256(
    const short* __restrict__ A, const short* __restrict__ B,
    const float* __restrict__ scaler, float* __restrict__ C,
    int M, int N, int K) {
  __shared__ alignas(16) char sm[131072];

  const int tid = threadIdx.x;
  const int l = tid & 63;
  const int w = tid >> 6;
  const int wr = w >> 2, wc = w & 3;
  const int ln15 = l & 15;

  // bijective XCD-aware swizzle (m204)
  const int nwg = gridDim.x;
  const int ntn = N >> 8;
  int bid = blockIdx.x;
  int q = nwg / NXCD, rr = nwg % NXCD;
  int xcd = bid % NXCD, idx = bid / NXCD;
  int swz = (xcd < rr ? xcd * (q + 1) : rr * (q + 1) + (xcd - rr) * q) + idx;
  const int m0 = (swz / ntn) << 8, n0 = (swz % ntn) << 8;

  const size_t ldkb = (size_t)K * 2;

  // --- staging per-thread bases (source pre-swizzled: rule 21) ---
  const int srow8 = l >> 3;
  const int sswz = ((l & 7) ^ srow8) << 4;
  const char* Ag = (const char*)A + (size_t)(m0 + w * 8 + srow8) * ldkb + sswz;
  const char* Bg = (const char*)B +
      (size_t)(n0 + (w >> 2) * 64 + (w & 3) * 8 + srow8) * ldkb + sswz;

  // --- read-side swizzled k offsets ---
  const int swzc = (l & 7) << 4;
  const int klo = (l >> 4) << 4;
  const int e45 = klo ^ (swzc & 48);
  const int s6 = swzc & 64;
  const int kof0 = e45 | s6;
  const int kof1 = e45 | (64 ^ s6);

  f32x4 acc[8][4] = {};                            // 128 acc regs
  short8v a0[8], a1[8], b0[4], b1[4];              // double-banked fragments

  const int NT = K >> 6;                           // K-tiles (even, >=2)

#define LDA8(buf, mh, dst) do {                                               \
    const char* _b = sm + (buf) * 65536 + ((mh)*128 + wr*64 + ln15) * 128;    \
    _Pragma("unroll") for (int f = 0; f < 4; ++f) {                           \
      dst[f*2+0] = *(const short8v*)(_b + f*2048 + kof0);                     \
      dst[f*2+1] = *(const short8v*)(_b + f*2048 + kof1); } } while (0)

#define LDB4(buf, nh, dst) do {                                               \
    const char* _b = sm + 32768 + (buf)*65536 + ((nh)*128 + wc*32 + ln15)*128;\
    _Pragma("unroll") for (int nf = 0; nf < 2; ++nf) {                        \
      dst[nf*2+0] = *(const short8v*)(_b + nf*2048 + kof0);                   \
      dst[nf*2+1] = *(const short8v*)(_b + nf*2048 + kof1); } } while (0)

#define STAGEA(buf, mh, tb) do {                                              \
    gl_lds16(Ag + (size_t)((mh)*64) * ldkb + (tb),                            \
             sm + (buf)*65536 + (mh)*16384 + w*1024);                         \
    gl_lds16(Ag + (size_t)((mh)*64 + 128) * ldkb + (tb),                      \
             sm + (buf)*65536 + (mh)*16384 + 8192 + w*1024); } while (0)

#define STAGEB(buf, nh, tb) do {                                              \
    gl_lds16(Bg + (size_t)((nh)*32) * ldkb + (tb),                            \
             sm + 32768 + (buf)*65536 + (nh)*16384 + w*1024);                 \
    gl_lds16(Bg + (size_t)((nh)*32 + 128) * ldkb + (tb),                      \
             sm + 32768 + (buf)*65536 + (nh)*16384 + 8192 + w*1024); } while (0)

#define MMAQ(mh, nh, av, bv) do {                                             \
    __builtin_amdgcn_s_setprio(1);                                            \
    _Pragma("unroll") for (int f = 0; f < 4; ++f)                             \
    _Pragma("unroll") for (int nf = 0; nf < 2; ++nf)                          \
    _Pragma("unroll") for (int ks = 0; ks < 2; ++ks)                          \
      acc[(mh)*4+f][(nh)*2+nf] = __builtin_amdgcn_mfma_f32_16x16x32_bf16(     \
          av[f*2+ks], bv[nf*2+ks], acc[(mh)*4+f][(nh)*2+nf], 0, 0, 0);        \
    __builtin_amdgcn_s_setprio(0); } while (0)

#define BAR() do { __builtin_amdgcn_sched_barrier(0);                         \
    asm volatile("s_barrier" ::: "memory");                                   \
    __builtin_amdgcn_sched_barrier(0); } while (0)

#define VMW(n) asm volatile("s_waitcnt vmcnt(" #n ")" ::: "memory")

  // prologue: stage tile0 + tile1 (16 loads); wait tile0 (8 left); prime regs
  STAGEA(0, 0, 0); STAGEB(0, 0, 0); STAGEB(0, 1, 0); STAGEA(0, 1, 0);
  {
    const size_t tbp = 128;
    STAGEA(1, 0, tbp); STAGEB(1, 0, tbp); STAGEB(1, 1, tbp); STAGEA(1, 1, tbp);
  }
  VMW(8);
  BAR();
  LDA8(0, 0, a0); LDB4(0, 0, b0);   // prime A0(t0), B0(t0)

  for (int t = 0; t < NT; t += 2) {
    const bool nx = (t + 2) < NT;
    const size_t tb2 = (size_t)(t + 2) << 7;
    const size_t tb3 = (size_t)(t + 3) << 7;
    // P1
    LDB4(0, 1, b1);                                   // B1(t)
    if (nx) { STAGEA(0, 0, tb2); STAGEB(0, 0, tb2); } // A0,B0(t+2)
    BAR();
    MMAQ(0, 0, a0, b0);
    BAR();
    // P2
    LDA8(0, 1, a1);                                   // A1(t)
    if (nx) STAGEB(0, 1, tb2);                        // B1(t+2)
    BAR();
    MMAQ(0, 1, a0, b1);
    BAR();
    // P3
    LDA8(1, 0, a0);                                   // A0(t+1)
    if (nx) STAGEA(0, 1, tb2);                        // A1(t+2)
    BAR();
    MMAQ(1, 0, a1, b0);
    BAR();
    // P4
    LDB4(1, 0, b0);                                   // B0(t+1)
    if (nx) STAGEA(1, 0, tb3);                        // A0(t+3)
    BAR();
    MMAQ(1, 1, a1, b1);
    if (nx) { VMW(6); } else { VMW(0); }
    BAR();
    // P5
    LDB4(1, 1, b1);                                   // B1(t+1)
    if (nx) STAGEB(1, 0, tb3);                        // B0(t+3)
    BAR();
    MMAQ(0, 0, a0, b0);
    BAR();
    // P6
    LDA8(1, 1, a1);                                   // A1(t+1)
    if (nx) STAGEB(1, 1, tb3);                        // B1(t+3)
    BAR();
    MMAQ(0, 1, a0, b1);
    BAR();
    // P7
    if (nx) LDA8(0, 0, a0);                           // A0(t+2)
    if (nx) STAGEA(1, 1, tb3);                        // A1(t+3)
    BAR();
    MMAQ(1, 0, a1, b0);
    BAR();
    // P8
    if (nx) LDB4(0, 0, b0);                           // B0(t+2)
    BAR();
    MMAQ(1, 1, a1, b1);
    if (nx) { VMW(4); } else { VMW(0); }
    BAR();
  }

  // epilogue: C row = m0+wr*128+mh*64+f*16+(l>>4)*4+j; col = n0+wc*64+nh*32+nf*16+ln15
  float scl[4];
#pragma unroll
  for (int ng = 0; ng < 4; ++ng)
    scl[ng] = scaler[n0 + wc * 64 + (ng >> 1) * 32 + (ng & 1) * 16 + ln15];
  const int row0 = m0 + wr * 128 + ((l >> 4) << 2);
  const int col0 = n0 + wc * 64 + ln15;
#pragma unroll
  for (int mf = 0; mf < 8; ++mf) {
    const int rbase = row0 + (mf >> 2) * 64 + (mf & 3) * 16;
#pragma unroll
    for (int j = 0; j < 4; ++j) {
      float* cp = C + (size_t)(rbase + j) * N + col0;
#pragma unroll
      for (int ng = 0; ng < 4; ++ng)
        cp[(ng >> 1) * 32 + (ng & 1) * 16] = acc[mf][ng][j] * scl[ng];
    }
  }
#undef LDA8
#undef LDB4
#undef STAGEA
#undef STAGEB
#undef MMAQ
#undef BAR
#undef VMW
}

// ---------------- fallback (no workspace needed) ----------------------------
#define FBM 128
#define FBN 128
#define FBK 32

__global__ __launch_bounds__(256) void gemm_fb(
    const float* __restrict__ A, const int* __restrict__ B,
    const float* __restrict__ scaler, float* __restrict__ C,
    int M, int N, int K) {
  __shared__ alignas(16) short As[FBM * FBK];
  __shared__ alignas(16) short Bs[FBN * FBK];

  const int tid = threadIdx.x;
  const int lane = tid & 63;
  const int wid = tid >> 6;
  const int wr = wid >> 1, wc = wid & 1;

  const int nwg = gridDim.x;
  const int ntn = N / FBN;
  int bid = blockIdx.x;
  int q = nwg / NXCD, r = nwg % NXCD;
  int xcd = bid % NXCD, idx = bid / NXCD;
  int swz = (xcd < r ? xcd * (q + 1) : r * (q + 1) + (xcd - r) * q) + idx;
  const int mt = swz / ntn, nt = swz % ntn;
  const int m0 = mt * FBM, n0 = nt * FBN;

  f32x4 acc[4][4] = {};
  const int kiters = K / FBK;

  for (int kt = 0; kt < kiters; ++kt) {
    const int k0 = kt * FBK;
    __syncthreads();
#pragma unroll
    for (int qq = 0; qq < 4; ++qq) {
      int chunk = qq * 256 + tid;
      int row = chunk >> 3;
      int c4 = (chunk & 7) * 4;
      float4 va = *(const float4*)&A[(size_t)(m0 + row) * K + k0 + c4];
      int4 vb = *(const int4*)&B[(size_t)(n0 + row) * K + k0 + c4];
      short4v wa, wb;
      wa[0] = bf16_bits(va.x); wa[1] = bf16_bits(va.y);
      wa[2] = bf16_bits(va.z); wa[3] = bf16_bits(va.w);
      wb[0] = bf16_bits((float)vb.x); wb[1] = bf16_bits((float)vb.y);
      wb[2] = bf16_bits((float)vb.z); wb[3] = bf16_bits((float)vb.w);
      *(short4v*)&As[row * FBK + c4] = wa;
      *(short4v*)&Bs[row * FBK + c4] = wb;
    }
    __syncthreads();
    const int ar = wr * 64 + (lane & 15);
    const int br = wc * 64 + (lane & 15);
    const int ko = (lane >> 4) * 8;
    short8v av[4], bv[4];
#pragma unroll
    for (int i = 0; i < 4; ++i) {
      av[i] = *(const short8v*)&As[(ar + i * 16) * FBK + ko];
      bv[i] = *(const short8v*)&Bs[(br + i * 16) * FBK + ko];
    }
#pragma unroll
    for (int mi = 0; mi < 4; ++mi)
#pragma unroll
      for (int ni = 0; ni < 4; ++ni)
        acc[mi][ni] = __builtin_amdgcn_mfma_f32_16x16x32_bf16(
            av[mi], bv[ni], acc[mi][ni], 0, 0, 0);
  }

  float sc[4];
  const int cc0 = n0 + wc * 64 + (lane & 15);
#pragma unroll
  for (int ni = 0; ni < 4; ++ni) sc[ni] = scaler[cc0 + ni * 16];
  const int cr0 = m0 + wr * 64 + ((lane >> 4) << 2);
#pragma unroll
  for (int mi = 0; mi < 4; ++mi)
#pragma unroll
    for (int j = 0; j < 4; ++j) {
      float* crow = C + (size_t)(cr0 + mi * 16 + j) * N;
#pragma unroll
      for (int ni = 0; ni < 4; ++ni)
        crow[cc0 + ni * 16] = acc[mi][ni][j] * sc[ni];
    }
}

// ---- conversion pre-passes (vectorized, grid-stride) -----------------------
__global__ void cvt_f32_bf16(const float* __restrict__ in,
                             short* __restrict__ out, long long n8) {
  long long i = (long long)blockIdx.x * blockDim.x + threadIdx.x;
  const long long stride = (long long)gridDim.x * blockDim.x;
  for (; i < n8; i += stride) {
    const float4* p = (const float4*)(in + i * 8);
    float4 va = p[0], vb = p[1];
    short8v o;
    o[0] = bf16_bits(va.x); o[1] = bf16_bits(va.y);
    o[2] = bf16_bits(va.z); o[3] = bf16_bits(va.w);
    o[4] = bf16_bits(vb.x); o[5] = bf16_bits(vb.y);
    o[6] = bf16_bits(vb.z); o[7] = bf16_bits(vb.w);
    *(short8v*)(out + i * 8) = o;
  }
}

__global__ void cvt_i32_bf16(const int* __restrict__ in,
                             short* __restrict__ out, long long n8) {
  long long i = (long long)blockIdx.x * blockDim.x + threadIdx.x;
  const long long stride = (long long)gridDim.x * blockDim.x;
  for (; i < n8; i += stride) {
    const int4* p = (const int4*)(in + i * 8);
    int4 va = p[0], vb = p[1];
    short8v o;
    o[0] = bf16_bits((float)va.x); o[1] = bf16_bits((float)va.y);
    o[2] = bf16_bits((float)va.z); o[3] = bf16_bits((float)va.w);
    o[4] = bf16_bits((float)vb.x); o[5] = bf16_bits((float)vb.y);
    o[6] = bf16_bits((float)vb.z); o[7] = bf16_bits((float)vb.w);
    *(short8v*)(out + i * 8) = o;
  }
}

extern "C" void kernel_launch(void* const* d_in, const int* in_sizes, int n_in,
                              void* d_out, int out_size, void* d_ws,
                              size_t ws_size, hipStream_t stream) {
  const float* x = (const float*)d_in[0];       // [M][K] fp32
  const int* w = (const int*)d_in[1];           // [N][K] int32 (int8 range)
  const float* sc = (const float*)d_in[2];      // [N] fp32
  float* out = (float*)d_out;                   // [M][N] fp32

  const long long xn = in_sizes[0];             // M*K
  const long long wn = in_sizes[1];             // N*K
  const int N = in_sizes[2];
  const int K = (int)(wn / N);
  const int M = (int)(xn / K);

  const size_t need = (size_t)(xn + wn) * sizeof(short);
  const bool ok256 = (M % 256 == 0) && (N % 256 == 0) && (K % 128 == 0);

  if (ws_size >= need && ok256) {
    short* xb = (short*)d_ws;                   // bf16 x
    short* wb = xb + xn;                        // bf16 w
    cvt_f32_bf16<<<2048, 256, 0, stream>>>(x, xb, xn / 8);
    cvt_i32_bf16<<<2048, 256, 0, stream>>>(w, wb, wn / 8);
    const int grid = (M / 256) * (N / 256);
    gemm256<<<grid, 512, 0, stream>>>(xb, wb, sc, out, M, N, K);
  } else {
    const int grid = (M / FBM) * (N / FBN);
    gemm_fb<<<grid, 256, 0, stream>>>(x, w, sc, out, M, N, K);
  }
}

// Round 5
// 713.734 us; speedup vs baseline: 1.3298x; 1.3298x over previous
//
#include <hip/hip_runtime.h>
#include <stdint.h>

// ---------------------------------------------------------------------------
// XlaQuantizedLinear: out[M,N] = (x[M,K] @ w[N,K]^T) * scaler[N]
// Round 5: 256x256 8-phase, SINGLE barrier per phase (wave-drift overlap).
// Round-4's reg-pipelining spilled (FETCH +76MB scratch); round-3's 45% util
// = serial {reads 576cy | MFMA 621cy | barriers} per phase. One barrier per
// phase lets reads(p+1) of fast waves overlap MFMA(p) of slow waves.
//
// Safety ledger (single barrier). Rule: stage(R)@p safe iff last-read(R)
// <= p-2 (reader's lgkm-wait precedes its MFMA(q), all waves pass BAR(q+1)
// before any wave's stage issued at front(p>=q+2)). Visibility rule:
// reader@q sees stage(R)@p iff some vmcnt retiring p's loads + a barrier
// lie between (vmcnt@P4/P8-front, published by BAR(P4)/BAR(P8)).
//
//  phase | reads (front)        | stage (front)     | vmcnt@front
//  P1    | 0.Ah0->a, 0.Bh0->b0  | 1.Bh1 (t+1)       |
//  P2    | 0.Bh1->b1            | 1.Ah1 (t+1)       |
//  P3    | 0.Ah1->a             | 0.Ah0 (t+2)       |
//  P4    | --                   | 0.Bh0 (t+2)       | vmcnt(2) [nx] else 0
//  P5    | 1.Ah0->a, 1.Bh0->b0  | 0.Ah1 (t+2)       |
//  P6    | 1.Bh1->b1            | 0.Bh1 (t+2)       |
//  P7    | 1.Ah1->a             | 1.Ah0 (t+3)       |
//  P8    | --                   | 1.Bh0 (t+3)       | vmcnt(2) [nx] else 0
// MFMA(p) = quadrant q00,q01,q10,q11 / buf0 then buf1, after BAR(p).
// vmcnt(2)@P4-front: outstanding {prevP7,prevP8,P1,P2,P3}=10 -> retires
//   prevP7..P2 = all buf1(t+1) regions; BAR(P4) publishes; reads P5/P6/P7 ok.
// vmcnt(2)@P8-front: outstanding {P3..P7}=10 -> retires P3..P6 = all
//   buf0(t+2); BAR(P8) publishes; reads next-P1/P2/P3 ok.
// WAR gaps: P1:3, P2:3, P3:2, P4:3, P5:2, P6:4, P7:2, P8:3  (all >=2). OK.
// Prologue: stage t0 (4 regions) + t1.{Ah0,Bh0}; vmcnt(4) -> t0 landed; BAR.
// ---------------------------------------------------------------------------

typedef __attribute__((ext_vector_type(8))) short short8v;  // 8 bf16
typedef __attribute__((ext_vector_type(4))) short short4v;
typedef __attribute__((ext_vector_type(4))) float f32x4;

#define NXCD 8

__device__ __forceinline__ short bf16_bits(float f) {
  uint32_t u = __builtin_bit_cast(uint32_t, f);
  uint32_t r = (u + 0x7FFFu + ((u >> 16) & 1u)) >> 16;
  return (short)r;
}

__device__ __forceinline__ void gl_lds16(const void* g, void* l) {
  __builtin_amdgcn_global_load_lds(
      (const __attribute__((address_space(1))) void*)g,
      (__attribute__((address_space(3))) void*)l, 16, 0, 0);
}

// LDS map (128KB): A(buf) at buf*65536 (32KB: [256 rows][128B]),
//                  B(buf) at 32768+buf*65536.
// A lds_row = mh*128 + wr*64 + r ; B lds_row = nh*128 + wc*32 + r
// swizzle: physical kbyte = logical kbyte ^ ((lds_row&7)<<4)  (involution)

__global__ __launch_bounds__(512, 2) void gemm256(
    const short* __restrict__ A, const short* __restrict__ B,
    const float* __restrict__ scaler, float* __restrict__ C,
    int M, int N, int K) {
  __shared__ alignas(16) char sm[131072];

  const int tid = threadIdx.x;
  const int l = tid & 63;
  const int w = tid >> 6;
  const int wr = w >> 2, wc = w & 3;
  const int ln15 = l & 15;

  // bijective XCD-aware swizzle (m204)
  const int nwg = gridDim.x;
  const int ntn = N >> 8;
  int bid = blockIdx.x;
  int q = nwg / NXCD, rr = nwg % NXCD;
  int xcd = bid % NXCD, idx = bid / NXCD;
  int swz = (xcd < rr ? xcd * (q + 1) : rr * (q + 1) + (xcd - rr) * q) + idx;
  const int m0 = (swz / ntn) << 8, n0 = (swz % ntn) << 8;

  const size_t ldkb = (size_t)K * 2;

  // --- staging per-thread bases (source pre-swizzled: rule 21) ---
  const int srow8 = l >> 3;
  const int sswz = ((l & 7) ^ srow8) << 4;
  const char* Ag = (const char*)A + (size_t)(m0 + w * 8 + srow8) * ldkb + sswz;
  const char* Bg = (const char*)B +
      (size_t)(n0 + (w >> 2) * 64 + (w & 3) * 8 + srow8) * ldkb + sswz;

  // --- read-side swizzled k offsets ---
  const int swzc = (l & 7) << 4;
  const int klo = (l >> 4) << 4;
  const int e45 = klo ^ (swzc & 48);
  const int s6 = swzc & 64;
  const int kof0 = e45 | s6;
  const int kof1 = e45 | (64 ^ s6);

  f32x4 acc[8][4] = {};                            // 128 acc regs
  short8v a[8], b0[4], b1[4];                      // 64 frag regs (round-3)

  const int NT = K >> 6;                           // K-tiles (even, >=2)

#define LDA8(buf, mh, dst) do {                                               \
    const char* _b = sm + (buf) * 65536 + ((mh)*128 + wr*64 + ln15) * 128;    \
    _Pragma("unroll") for (int f = 0; f < 4; ++f) {                           \
      dst[f*2+0] = *(const short8v*)(_b + f*2048 + kof0);                     \
      dst[f*2+1] = *(const short8v*)(_b + f*2048 + kof1); } } while (0)

#define LDB4(buf, nh, dst) do {                                               \
    const char* _b = sm + 32768 + (buf)*65536 + ((nh)*128 + wc*32 + ln15)*128;\
    _Pragma("unroll") for (int nf = 0; nf < 2; ++nf) {                        \
      dst[nf*2+0] = *(const short8v*)(_b + nf*2048 + kof0);                   \
      dst[nf*2+1] = *(const short8v*)(_b + nf*2048 + kof1); } } while (0)

#define STAGEA(buf, mh, tb) do {                                              \
    gl_lds16(Ag + (size_t)((mh)*64) * ldkb + (tb),                            \
             sm + (buf)*65536 + (mh)*16384 + w*1024);                         \
    gl_lds16(Ag + (size_t)((mh)*64 + 128) * ldkb + (tb),                      \
             sm + (buf)*65536 + (mh)*16384 + 8192 + w*1024); } while (0)

#define STAGEB(buf, nh, tb) do {                                              \
    gl_lds16(Bg + (size_t)((nh)*32) * ldkb + (tb),                            \
             sm + 32768 + (buf)*65536 + (nh)*16384 + w*1024);                 \
    gl_lds16(Bg + (size_t)((nh)*32 + 128) * ldkb + (tb),                      \
             sm + 32768 + (buf)*65536 + (nh)*16384 + 8192 + w*1024); } while (0)

#define MMAQ(mh, nh, av, bv) do {                                             \
    __builtin_amdgcn_s_setprio(1);                                            \
    _Pragma("unroll") for (int f = 0; f < 4; ++f)                             \
    _Pragma("unroll") for (int nf = 0; nf < 2; ++nf)                          \
    _Pragma("unroll") for (int ks = 0; ks < 2; ++ks)                          \
      acc[(mh)*4+f][(nh)*2+nf] = __builtin_amdgcn_mfma_f32_16x16x32_bf16(     \
          av[f*2+ks], bv[nf*2+ks], acc[(mh)*4+f][(nh)*2+nf], 0, 0, 0);        \
    __builtin_amdgcn_s_setprio(0); } while (0)

#define BAR() do { __builtin_amdgcn_sched_barrier(0);                         \
    asm volatile("s_barrier" ::: "memory");                                   \
    __builtin_amdgcn_sched_barrier(0); } while (0)

#define VMW(n) asm volatile("s_waitcnt vmcnt(" #n ")" ::: "memory")

  // prologue: tile0 (4 regions) + tile1.{Ah0,Bh0}; wait tile0; publish
  STAGEA(0, 0, 0); STAGEB(0, 0, 0); STAGEA(0, 1, 0); STAGEB(0, 1, 0);
  {
    const size_t tbp = 128;  // tile 1 byte offset
    STAGEA(1, 0, tbp); STAGEB(1, 0, tbp);
  }
  VMW(4);
  BAR();

  for (int t = 0; t < NT; t += 2) {
    const bool nx = (t + 2) < NT;
    const size_t tb1 = (size_t)(t + 1) << 7;
    const size_t tb2 = (size_t)(t + 2) << 7;
    const size_t tb3 = (size_t)(t + 3) << 7;
    // P1
    LDA8(0, 0, a); LDB4(0, 0, b0);
    STAGEB(1, 1, tb1);
    BAR();
    MMAQ(0, 0, a, b0);
    // P2
    LDB4(0, 1, b1);
    STAGEA(1, 1, tb1);
    BAR();
    MMAQ(0, 1, a, b1);
    // P3
    LDA8(0, 1, a);
    if (nx) STAGEA(0, 0, tb2);
    BAR();
    MMAQ(1, 0, a, b0);
    // P4
    if (nx) { VMW(2); STAGEB(0, 0, tb2); } else { VMW(0); }
    BAR();
    MMAQ(1, 1, a, b1);
    // P5
    LDA8(1, 0, a); LDB4(1, 0, b0);
    if (nx) STAGEA(0, 1, tb2);
    BAR();
    MMAQ(0, 0, a, b0);
    // P6
    LDB4(1, 1, b1);
    if (nx) STAGEB(0, 1, tb2);
    BAR();
    MMAQ(0, 1, a, b1);
    // P7
    LDA8(1, 1, a);
    if (nx) STAGEA(1, 0, tb3);
    BAR();
    MMAQ(1, 0, a, b0);
    // P8
    if (nx) { VMW(2); STAGEB(1, 0, tb3); } else { VMW(0); }
    BAR();
    MMAQ(1, 1, a, b1);
  }

  // epilogue: C row = m0+wr*128+mh*64+f*16+(l>>4)*4+j; col = n0+wc*64+nh*32+nf*16+ln15
  float scl[4];
#pragma unroll
  for (int ng = 0; ng < 4; ++ng)
    scl[ng] = scaler[n0 + wc * 64 + (ng >> 1) * 32 + (ng & 1) * 16 + ln15];
  const int row0 = m0 + wr * 128 + ((l >> 4) << 2);
  const int col0 = n0 + wc * 64 + ln15;
#pragma unroll
  for (int mf = 0; mf < 8; ++mf) {
    const int rbase = row0 + (mf >> 2) * 64 + (mf & 3) * 16;
#pragma unroll
    for (int j = 0; j < 4; ++j) {
      float* cp = C + (size_t)(rbase + j) * N + col0;
#pragma unroll
      for (int ng = 0; ng < 4; ++ng)
        cp[(ng >> 1) * 32 + (ng & 1) * 16] = acc[mf][ng][j] * scl[ng];
    }
  }
#undef LDA8
#undef LDB4
#undef STAGEA
#undef STAGEB
#undef MMAQ
#undef BAR
#undef VMW
}

// ---------------- fallback (no workspace needed) ----------------------------
#define FBM 128
#define FBN 128
#define FBK 32

__global__ __launch_bounds__(256) void gemm_fb(
    const float* __restrict__ A, const int* __restrict__ B,
    const float* __restrict__ scaler, float* __restrict__ C,
    int M, int N, int K) {
  __shared__ alignas(16) short As[FBM * FBK];
  __shared__ alignas(16) short Bs[FBN * FBK];

  const int tid = threadIdx.x;
  const int lane = tid & 63;
  const int wid = tid >> 6;
  const int wr = wid >> 1, wc = wid & 1;

  const int nwg = gridDim.x;
  const int ntn = N / FBN;
  int bid = blockIdx.x;
  int q = nwg / NXCD, r = nwg % NXCD;
  int xcd = bid % NXCD, idx = bid / NXCD;
  int swz = (xcd < r ? xcd * (q + 1) : r * (q + 1) + (xcd - r) * q) + idx;
  const int mt = swz / ntn, nt = swz % ntn;
  const int m0 = mt * FBM, n0 = nt * FBN;

  f32x4 acc[4][4] = {};
  const int kiters = K / FBK;

  for (int kt = 0; kt < kiters; ++kt) {
    const int k0 = kt * FBK;
    __syncthreads();
#pragma unroll
    for (int qq = 0; qq < 4; ++qq) {
      int chunk = qq * 256 + tid;
      int row = chunk >> 3;
      int c4 = (chunk & 7) * 4;
      float4 va = *(const float4*)&A[(size_t)(m0 + row) * K + k0 + c4];
      int4 vb = *(const int4*)&B[(size_t)(n0 + row) * K + k0 + c4];
      short4v wa, wb;
      wa[0] = bf16_bits(va.x); wa[1] = bf16_bits(va.y);
      wa[2] = bf16_bits(va.z); wa[3] = bf16_bits(va.w);
      wb[0] = bf16_bits((float)vb.x); wb[1] = bf16_bits((float)vb.y);
      wb[2] = bf16_bits((float)vb.z); wb[3] = bf16_bits((float)vb.w);
      *(short4v*)&As[row * FBK + c4] = wa;
      *(short4v*)&Bs[row * FBK + c4] = wb;
    }
    __syncthreads();
    const int ar = wr * 64 + (lane & 15);
    const int br = wc * 64 + (lane & 15);
    const int ko = (lane >> 4) * 8;
    short8v av[4], bv[4];
#pragma unroll
    for (int i = 0; i < 4; ++i) {
      av[i] = *(const short8v*)&As[(ar + i * 16) * FBK + ko];
      bv[i] = *(const short8v*)&Bs[(br + i * 16) * FBK + ko];
    }
#pragma unroll
    for (int mi = 0; mi < 4; ++mi)
#pragma unroll
      for (int ni = 0; ni < 4; ++ni)
        acc[mi][ni] = __builtin_amdgcn_mfma_f32_16x16x32_bf16(
            av[mi], bv[ni], acc[mi][ni], 0, 0, 0);
  }

  float sc[4];
  const int cc0 = n0 + wc * 64 + (lane & 15);
#pragma unroll
  for (int ni = 0; ni < 4; ++ni) sc[ni] = scaler[cc0 + ni * 16];
  const int cr0 = m0 + wr * 64 + ((lane >> 4) << 2);
#pragma unroll
  for (int mi = 0; mi < 4; ++mi)
#pragma unroll
    for (int j = 0; j < 4; ++j) {
      float* crow = C + (size_t)(cr0 + mi * 16 + j) * N;
#pragma unroll
      for (int ni = 0; ni < 4; ++ni)
        crow[cc0 + ni * 16] = acc[mi][ni][j] * sc[ni];
    }
}

// ---- conversion pre-passes (vectorized, grid-stride) -----------------------
__global__ void cvt_f32_bf16(const float* __restrict__ in,
                             short* __restrict__ out, long long n8) {
  long long i = (long long)blockIdx.x * blockDim.x + threadIdx.x;
  const long long stride = (long long)gridDim.x * blockDim.x;
  for (; i < n8; i += stride) {
    const float4* p = (const float4*)(in + i * 8);
    float4 va = p[0], vb = p[1];
    short8v o;
    o[0] = bf16_bits(va.x); o[1] = bf16_bits(va.y);
    o[2] = bf16_bits(va.z); o[3] = bf16_bits(va.w);
    o[4] = bf16_bits(vb.x); o[5] = bf16_bits(vb.y);
    o[6] = bf16_bits(vb.z); o[7] = bf16_bits(vb.w);
    *(short8v*)(out + i * 8) = o;
  }
}

__global__ void cvt_i32_bf16(const int* __restrict__ in,
                             short* __restrict__ out, long long n8) {
  long long i = (long long)blockIdx.x * blockDim.x + threadIdx.x;
  const long long stride = (long long)gridDim.x * blockDim.x;
  for (; i < n8; i += stride) {
    const int4* p = (const int4*)(in + i * 8);
    int4 va = p[0], vb = p[1];
    short8v o;
    o[0] = bf16_bits((float)va.x); o[1] = bf16_bits((float)va.y);
    o[2] = bf16_bits((float)va.z); o[3] = bf16_bits((float)va.w);
    o[4] = bf16_bits((float)vb.x); o[5] = bf16_bits((float)vb.y);
    o[6] = bf16_bits((float)vb.z); o[7] = bf16_bits((float)vb.w);
    *(short8v*)(out + i * 8) = o;
  }
}

extern "C" void kernel_launch(void* const* d_in, const int* in_sizes, int n_in,
                              void* d_out, int out_size, void* d_ws,
                              size_t ws_size, hipStream_t stream) {
  const float* x = (const float*)d_in[0];       // [M][K] fp32
  const int* w = (const int*)d_in[1];           // [N][K] int32 (int8 range)
  const float* sc = (const float*)d_in[2];      // [N] fp32
  float* out = (float*)d_out;                   // [M][N] fp32

  const long long xn = in_sizes[0];             // M*K
  const long long wn = in_sizes[1];             // N*K
  const int N = in_sizes[2];
  const int K = (int)(wn / N);
  const int M = (int)(xn / K);

  const size_t need = (size_t)(xn + wn) * sizeof(short);
  const bool ok256 = (M % 256 == 0) && (N % 256 == 0) && (K % 128 == 0);

  if (ws_size >= need && ok256) {
    short* xb = (short*)d_ws;                   // bf16 x
    short* wb = xb + xn;                        // bf16 w
    cvt_f32_bf16<<<2048, 256, 0, stream>>>(x, xb, xn / 8);
    cvt_i32_bf16<<<2048, 256, 0, stream>>>(w, wb, wn / 8);
    const int grid = (M / 256) * (N / 256);
    gemm256<<<grid, 512, 0, stream>>>(xb, wb, sc, out, M, N, K);
  } else {
    const int grid = (M / FBM) * (N / FBN);
    gemm_fb<<<grid, 256, 0, stream>>>(x, w, sc, out, M, N, K);
  }
}